// Round 1
// baseline (356.269 us; speedup 1.0000x reference)
//
#include <hip/hip_runtime.h>
#include <stdint.h>

// MultiAttention fused kernel for MI355X (gfx950)
// B=131072 rows; D=105 (80 hm + 20 me + 5 tf); 10 attention groups.
// out  [B,105] fp32  (first 13,762,560 floats of d_out)
// alpha[B,1050] fp32 (next 137,625,600 floats of d_out)

#define NATT 10
#define DD   105
#define NPAD 112          // padded group width (7 x 16)
#define KP   136          // k pitch in elements (128 used + 8 pad -> bank-conflict-free b128)
#define RPB  128          // rows per block
#define GRP_ELEMS (NPAD*KP)        // 15232 bf16 per group slab
#define GRP_B16   (GRP_ELEMS*2/16) // 1904 16B chunks

typedef __attribute__((ext_vector_type(8))) short short8v;  // 8 bf16 = MFMA A/B frag
typedef __attribute__((ext_vector_type(4))) short short4v;
typedef __attribute__((ext_vector_type(4))) float f4;
typedef __attribute__((ext_vector_type(4))) unsigned int u32x4;

__device__ __forceinline__ short f2bf(float x) {
  unsigned int u = __builtin_bit_cast(unsigned int, x);
  unsigned int r = (u + 0x7FFFu + ((u >> 16) & 1u)) >> 16;   // RNE
  return (short)(r & 0xFFFFu);
}
__device__ __forceinline__ float bf2f(int b) {
  unsigned int u = ((unsigned int)(b & 0xFFFF)) << 16;
  return __builtin_bit_cast(float, u);
}

// ---------------- prep: build bf16 packs in workspace ----------------
// Apack [g][n<112][k<136]: A_w[105g+n][k], zeros outside (n<105,k<105)
// Wpack [g][j<112][il' swizzled]: block-diag [HM|ME|TF] weights at absolute col 105g+il,
//        stored in kappa2 order so GEMM2 B-frag is one contiguous b128:
//        il'(cc,gg,jj) = cc*32+gg*8+jj  holds il = cc*32 + 4*gg + (jj&3) + 16*(jj>>2)
// Abp   [g][n<112] fp32: A_b, pad = -1e30 (masks softmax pad cols)
// Bout  [112] fp32: [HM_b|ME_b|TF_b|0]
// Lut   [1152] u16: expanded-column -> ctx column map
__global__ void prep_kernel(const float* __restrict__ Aw, const float* __restrict__ Ab,
                            const float* __restrict__ HMw, const float* __restrict__ HMb,
                            const float* __restrict__ MEw, const float* __restrict__ MEb,
                            const float* __restrict__ TFw, const float* __restrict__ TFb,
                            short* __restrict__ Apack, short* __restrict__ Wpack,
                            float* __restrict__ Abp, float* __restrict__ Bout,
                            unsigned short* __restrict__ Lut)
{
  int tid = blockIdx.x * blockDim.x + threadIdx.x;
  int NT  = gridDim.x * blockDim.x;

  for (int a = tid; a < NATT * GRP_ELEMS; a += NT) {
    int g = a / GRP_ELEMS; int rem = a - g * GRP_ELEMS;
    int n = rem / KP;      int k   = rem - n * KP;
    float v = 0.f;
    if (n < DD && k < DD) v = Aw[(g * DD + n) * DD + k];
    Apack[a] = f2bf(v);
  }

  for (int a = tid; a < NATT * GRP_ELEMS; a += NT) {
    int g = a / GRP_ELEMS; int rem = a - g * GRP_ELEMS;
    int j = rem / KP;      int ilp = rem - j * KP;
    float v = 0.f;
    if (ilp < 128 && j < DD) {
      int cc = ilp >> 5, r2 = ilp & 31, gg = r2 >> 3, jj = r2 & 7;
      int il = cc * 32 + gg * 4 + (jj & 3) + ((jj >> 2) << 4);
      int i  = g * DD + il;
      if (i < 1050) {
        if (i < 800)       { if (j < 80)             v = HMw[j * 800 + i]; }
        else if (i < 1000) { if (j >= 80 && j < 100) v = MEw[(j - 80) * 200 + (i - 800)]; }
        else               { if (j >= 100)           v = TFw[(j - 100) * 50 + (i - 1000)]; }
      }
    }
    Wpack[a] = f2bf(v);
  }

  for (int a = tid; a < NATT * NPAD; a += NT) {
    int g = a / NPAD; int n = a - g * NPAD;
    Abp[a] = (n < DD) ? Ab[g * DD + n] : -1e30f;
  }

  for (int a = tid; a < NPAD; a += NT) {
    float v = 0.f;
    if (a < 80) v = HMb[a];
    else if (a < 100) v = MEb[a - 80];
    else if (a < DD)  v = TFb[a - 100];
    Bout[a] = v;
  }

  for (int a = tid; a < 1152; a += NT) {
    int col;
    if (a < 800)       col = a % 80;
    else if (a < 1000) col = 80 + (a - 800) % 20;
    else if (a < 1050) col = 100 + (a - 1000) % 5;
    else               col = 100;  // only reached where alpha==0
    Lut[a] = (unsigned short)col;
  }
}

// ---------------- main fused kernel ----------------
// 1024 blocks x 256 threads; 4 waves x 32 rows each.
// LDS: sCtx 128x136 bf16 (34816B) + sW 112x136 bf16 (30464B) = 65280B (2 blocks/CU).
__global__ __launch_bounds__(256, 2)
void fused_main(const float* __restrict__ hm, const float* __restrict__ me,
                const float* __restrict__ tf,
                const short* __restrict__ Apack, const short* __restrict__ Wpack,
                const float* __restrict__ Abp, const float* __restrict__ Bout,
                const unsigned short* __restrict__ Lut,
                float* __restrict__ out, float* __restrict__ alphaOut)
{
  __shared__ short sCtx[RPB * KP];
  __shared__ short sW[NPAD * KP];

  const int tid  = threadIdx.x;
  const int lane = tid & 63;
  const int wave = tid >> 6;
  const int l15  = lane & 15;
  const int g16  = lane >> 4;
  const long rowbase = (long)blockIdx.x * RPB;

  // ---- stage ctx tile as bf16: [row][0..79]=hm [80..99]=me [100..104]=tf [105..135]=0 ----
  for (int q = tid; q < (RPB * 80) / 4; q += 256) {
    f4 v = *(const f4*)(hm + rowbase * 80 + q * 4);
    int r = (q * 4) / 80, c = (q * 4) % 80;
    short4v b; b[0]=f2bf(v[0]); b[1]=f2bf(v[1]); b[2]=f2bf(v[2]); b[3]=f2bf(v[3]);
    *(short4v*)&sCtx[r * KP + c] = b;
  }
  for (int q = tid; q < (RPB * 20) / 4; q += 256) {
    f4 v = *(const f4*)(me + rowbase * 20 + q * 4);
    int r = (q * 4) / 20, c = (q * 4) % 20;
    short4v b; b[0]=f2bf(v[0]); b[1]=f2bf(v[1]); b[2]=f2bf(v[2]); b[3]=f2bf(v[3]);
    *(short4v*)&sCtx[r * KP + 80 + c] = b;
  }
  for (int q = tid; q < RPB * 5; q += 256) {
    float v = tf[rowbase * 5 + q];
    int r = q / 5, c = q - r * 5;
    sCtx[r * KP + 100 + c] = f2bf(v);
  }
  for (int q = tid; q < RPB * 31; q += 256) {
    int r = q / 31, c = q - r * 31;
    sCtx[r * KP + 105 + c] = 0;
  }

  f4 acc2[2][7];
  #pragma unroll
  for (int rt = 0; rt < 2; ++rt)
    #pragma unroll
    for (int jt = 0; jt < 7; ++jt) {
      acc2[rt][jt][0]=0.f; acc2[rt][jt][1]=0.f; acc2[rt][jt][2]=0.f; acc2[rt][jt][3]=0.f;
    }

  short8v hf[2][4];   // h fragments (GEMM2 A operand), per row-tile, per 32-wide k chunk

  for (int g = 0; g < NATT; ++g) {
    __syncthreads();                       // prior G2 done with sW / ctx staging done (g=0)
    {
      const u32x4* src = (const u32x4*)(Apack + g * GRP_ELEMS);
      u32x4* dst = (u32x4*)sW;
      for (int q = tid; q < GRP_B16; q += 256) dst[q] = src[q];
    }
    __syncthreads();

    // ---- GEMM1 (swapped): z^T tile; D[n][r], n=16T+4*g16+reg, r=l15 ----
    f4 za[2][7];
    #pragma unroll
    for (int rt = 0; rt < 2; ++rt)
      #pragma unroll
      for (int T = 0; T < 7; ++T) { za[rt][T][0]=0.f; za[rt][T][1]=0.f; za[rt][T][2]=0.f; za[rt][T][3]=0.f; }

    #pragma unroll
    for (int c = 0; c < 4; ++c) {
      short8v cf0 = *(const short8v*)&sCtx[(wave * 32 +      l15) * KP + c * 32 + g16 * 8];
      short8v cf1 = *(const short8v*)&sCtx[(wave * 32 + 16 + l15) * KP + c * 32 + g16 * 8];
      #pragma unroll
      for (int T = 0; T < 7; ++T) {
        short8v af = *(const short8v*)&sW[(T * 16 + l15) * KP + c * 32 + g16 * 8];
        za[0][T] = __builtin_amdgcn_mfma_f32_16x16x32_bf16(af, cf0, za[0][T], 0, 0, 0);
        za[1][T] = __builtin_amdgcn_mfma_f32_16x16x32_bf16(af, cf1, za[1][T], 0, 0, 0);
      }
    }

    f4 ab4[7];
    #pragma unroll
    for (int T = 0; T < 7; ++T)
      ab4[T] = *(const f4*)(Abp + g * NPAD + T * 16 + g16 * 4);

    // ---- softmax + alpha store + h build (per 16-row tile) ----
    #pragma unroll
    for (int rt = 0; rt < 2; ++rt) {
      float z[7][4];
      float mx = -3e38f;
      #pragma unroll
      for (int T = 0; T < 7; ++T)
        #pragma unroll
        for (int k = 0; k < 4; ++k) {
          float v = za[rt][T][k] + ab4[T][k];   // pad cols get -1e30 -> masked
          z[T][k] = v;
          mx = fmaxf(mx, v);
        }
      mx = fmaxf(mx, __shfl_xor(mx, 16));
      mx = fmaxf(mx, __shfl_xor(mx, 32));
      float s = 0.f;
      #pragma unroll
      for (int T = 0; T < 7; ++T)
        #pragma unroll
        for (int k = 0; k < 4; ++k) {
          float p = __expf(z[T][k] - mx);
          z[T][k] = p;
          s += p;
        }
      s += __shfl_xor(s, 16);
      s += __shfl_xor(s, 32);
      float inv = __fdividef(1.f, s);

      const int rowl = wave * 32 + rt * 16 + l15;
      float* arow = alphaOut + (rowbase + rowl) * 1050 + g * DD;

      hf[rt][3][4] = 0; hf[rt][3][5] = 0; hf[rt][3][6] = 0; hf[rt][3][7] = 0; // T=7 half
      #pragma unroll
      for (int T = 0; T < 7; ++T) {
        #pragma unroll
        for (int k = 0; k < 4; ++k) {
          float a = z[T][k] * inv;
          int n = T * 16 + g16 * 4 + k;
          if (T < 6)        arow[n] = a;
          else if (n < DD)  arow[n] = a;
          int i = g * DD + n;                       // absolute expanded column
          int col = Lut[i];                          // ctx column (L1-hot 2.3KB LUT)
          float e = bf2f(sCtx[rowl * KP + col]);     // gather modality value
          short hb = f2bf(a * e);
          hf[rt][T >> 1][(T & 1) * 4 + k] = hb;      // kappa2 slot
        }
      }
    }

    __syncthreads();                       // all waves done reading sW (Apack)
    {
      const u32x4* src = (const u32x4*)(Wpack + g * GRP_ELEMS);
      u32x4* dst = (u32x4*)sW;
      for (int q = tid; q < GRP_B16; q += 256) dst[q] = src[q];
    }
    __syncthreads();

    // ---- GEMM2 accumulate: out[r][j] += sum_il h[r][105g+il] * Wall[j][105g+il] ----
    #pragma unroll
    for (int cc = 0; cc < 4; ++cc) {
      #pragma unroll
      for (int jt = 0; jt < 7; ++jt) {
        short8v wf = *(const short8v*)&sW[(jt * 16 + l15) * KP + cc * 32 + g16 * 8];
        acc2[0][jt] = __builtin_amdgcn_mfma_f32_16x16x32_bf16(hf[0][cc], wf, acc2[0][jt], 0, 0, 0);
        acc2[1][jt] = __builtin_amdgcn_mfma_f32_16x16x32_bf16(hf[1][cc], wf, acc2[1][jt], 0, 0, 0);
      }
    }
  }

  // ---- epilogue: out = acc2 + bias; D2[r][j]: r = rt*16+4*g16+k, j = 16*jt+l15 ----
  #pragma unroll
  for (int jt = 0; jt < 7; ++jt) {
    int j = jt * 16 + l15;
    if (j < DD) {
      float bj = Bout[j];
      #pragma unroll
      for (int rt = 0; rt < 2; ++rt)
        #pragma unroll
        for (int k = 0; k < 4; ++k) {
          long row = rowbase + wave * 32 + rt * 16 + g16 * 4 + k;
          out[row * DD + j] = acc2[rt][jt][k] + bj;
        }
    }
  }
}

// ---------------- launch ----------------
extern "C" void kernel_launch(void* const* d_in, const int* in_sizes, int n_in,
                              void* d_out, int out_size, void* d_ws, size_t ws_size,
                              hipStream_t stream)
{
  const float* hm  = (const float*)d_in[0];
  const float* me  = (const float*)d_in[1];
  const float* tf  = (const float*)d_in[2];
  const float* Aw  = (const float*)d_in[3];
  const float* Ab  = (const float*)d_in[4];
  const float* HMw = (const float*)d_in[5];
  const float* HMb = (const float*)d_in[6];
  const float* MEw = (const float*)d_in[7];
  const float* MEb = (const float*)d_in[8];
  const float* TFw = (const float*)d_in[9];
  const float* TFb = (const float*)d_in[10];

  char* ws = (char*)d_ws;
  short* Apack = (short*)(ws + 0);                 // 304640 B
  short* Wpack = (short*)(ws + 304640);            // 304640 B
  float* Abp   = (float*)(ws + 609280);            // 4480 B
  float* BoutP = (float*)(ws + 613760);            // 448 B
  unsigned short* Lut = (unsigned short*)(ws + 614208); // 2304 B  (total 616512)

  float* outP     = (float*)d_out;
  float* alphaOut = outP + (long)131072 * DD;

  prep_kernel<<<320, 256, 0, stream>>>(Aw, Ab, HMw, HMb, MEw, MEb, TFw, TFb,
                                       Apack, Wpack, Abp, BoutP, Lut);
  fused_main<<<1024, 256, 0, stream>>>(hm, me, tf, Apack, Wpack, Abp, BoutP, Lut,
                                       outP, alphaOut);
}